// Round 1
// baseline (642.565 us; speedup 1.0000x reference)
//
#include <hip/hip_runtime.h>
#include <hip/hip_bf16.h>
#include <stdint.h>

#define D_IN 4096
#define TOKENS 2048
#define NUM_LATENTS 65536
#define GROUP_DIM 64
#define GROUP_MUL 4
#define IN_GROUPS 64
#define OUT_GROUPS 1024
#define KMID 256   // GROUP_MUL * IN_GROUPS

typedef __attribute__((ext_vector_type(8))) short short8;
typedef __attribute__((ext_vector_type(4))) float f32x4;

struct alignas(8) US4 { unsigned short v[4]; };

__device__ inline unsigned short f2bf(float f) {
    union { float f; unsigned u; } w{f};
    unsigned r = w.u + 0x7fffu + ((w.u >> 16) & 1u);  // RNE
    return (unsigned short)(r >> 16);
}

__device__ inline void gload_lds16(const void* g, void* l) {
    __builtin_amdgcn_global_load_lds(
        (const __attribute__((address_space(1))) void*)g,
        (__attribute__((address_space(3))) void*)l, 16, 0, 0);
}

// ---------------- convert f32 -> bf16 (vectorized) ----------------
__global__ void cvt_bf16(const float* __restrict__ s, unsigned short* __restrict__ d, int n4) {
    int i = blockIdx.x * blockDim.x + threadIdx.x;
    if (i < n4) {
        f32x4 v = *(const f32x4*)(s + (size_t)i * 4);
        US4 o;
        #pragma unroll
        for (int j = 0; j < 4; ++j) o.v[j] = f2bf(v[j]);
        *(US4*)(d + (size_t)i * 4) = o;
    }
}

// ---------------- stage 1: h = x @ W^T + b   (bf16 MFMA, 128x128x64) -------
__global__ __launch_bounds__(256) void gemm_pre(
    const unsigned short* __restrict__ A,   // x_bf  [2048][4096]
    const unsigned short* __restrict__ B,   // w_bf  [4096][4096] row n, col k
    const float* __restrict__ bias,         // [4096]
    unsigned short* __restrict__ H)         // h_bf  [2048][4096]
{
    __shared__ unsigned short As[128 * 64];
    __shared__ unsigned short Bs[128 * 64];
    const int tid = threadIdx.x;
    const int lane = tid & 63;
    const int w = tid >> 6;
    const int wm = w >> 1, wn = w & 1;
    const int bx = blockIdx.x;
    const int m0 = (bx & 15) * 128;   // 16 m-tiles fast: share B panel in L2
    const int n0 = (bx >> 4) * 128;   // 32 n-tiles

    const int lr = lane & 15;
    const int lk = (lane >> 4) * 8;

    f32x4 acc[4][4] = {};

    for (int k0 = 0; k0 < D_IN; k0 += 64) {
        #pragma unroll
        for (int c = 0; c < 4; ++c) {
            int f = c * 2048 + tid * 8;     // element offset in 128x64 tile
            int r = f >> 6, col = f & 63;
            gload_lds16(A + (size_t)(m0 + r) * D_IN + k0 + col, As + f);
            gload_lds16(B + (size_t)(n0 + r) * D_IN + k0 + col, Bs + f);
        }
        asm volatile("s_waitcnt vmcnt(0)" ::: "memory");
        __syncthreads();
        #pragma unroll
        for (int kk = 0; kk < 2; ++kk) {
            short8 a[4], b[4];
            #pragma unroll
            for (int mi = 0; mi < 4; ++mi)
                a[mi] = *(const short8*)(As + (wm * 64 + mi * 16 + lr) * 64 + kk * 32 + lk);
            #pragma unroll
            for (int ni = 0; ni < 4; ++ni)
                b[ni] = *(const short8*)(Bs + (wn * 64 + ni * 16 + lr) * 64 + kk * 32 + lk);
            #pragma unroll
            for (int mi = 0; mi < 4; ++mi)
                #pragma unroll
                for (int ni = 0; ni < 4; ++ni)
                    acc[mi][ni] = __builtin_amdgcn_mfma_f32_16x16x32_bf16(a[mi], b[ni], acc[mi][ni], 0, 0, 0);
        }
        __syncthreads();
    }

    const int rin = (lane >> 4) * 4;
    #pragma unroll
    for (int ni = 0; ni < 4; ++ni) {
        int col = n0 + wn * 64 + ni * 16 + lr;
        float bv = bias[col];
        #pragma unroll
        for (int mi = 0; mi < 4; ++mi) {
            #pragma unroll
            for (int j = 0; j < 4; ++j) {
                int row = m0 + wm * 64 + mi * 16 + rin + j;
                H[(size_t)row * D_IN + col] = f2bf(acc[mi][ni][j] + bv);
            }
        }
    }
}

// ---------------- stage 2: t2[(b*64+y)][(m*64+i)] = sum_x h[b,i,x] inner[m,i,x,y]
// one block per (i, 64-row b-tile); wave w handles m=w.
__global__ __launch_bounds__(256) void stage2(
    const unsigned short* __restrict__ H,   // [2048][4096] bf16
    const float* __restrict__ inner,        // [4][64][64][64] f32
    unsigned short* __restrict__ T)         // [131072][256] bf16
{
    __shared__ unsigned short hs[64][80];        // padded: stride 160B -> <=4-way conflict
    __shared__ unsigned short innT[4][64][80];   // [m][y][x]
    const int tid = threadIdx.x;
    const int lane = tid & 63;
    const int w = tid >> 6;      // = m
    const int bx = blockIdx.x;
    const int i = bx & 63;
    const int b0 = (bx >> 6) * 64;

    // h tile 64x64 -> padded LDS
    {
        int r = tid >> 2, c = (tid & 3) * 16;
        const unsigned short* src = H + (size_t)(b0 + r) * D_IN + i * 64 + c;
        short8 v0 = *(const short8*)(src);
        short8 v1 = *(const short8*)(src + 8);
        *(short8*)(&hs[r][c]) = v0;
        *(short8*)(&hs[r][c + 8]) = v1;
    }
    // inner[m][i] transposed -> innT[m][y][x], bf16
    {
        const float* src = inner + ((size_t)w * 64 + i) * 4096;  // [x][y]
        #pragma unroll
        for (int p = 0; p < 16; ++p) {
            int idx = p * 256 + lane * 4;
            int x = idx >> 6, y = idx & 63;
            f32x4 v = *(const f32x4*)(src + idx);
            #pragma unroll
            for (int j = 0; j < 4; ++j) innT[w][y + j][x] = f2bf(v[j]);
        }
    }
    __syncthreads();

    const int lr = lane & 15;
    const int lk = (lane >> 4) * 8;
    f32x4 acc[4][4] = {};
    #pragma unroll
    for (int kk = 0; kk < 2; ++kk) {
        short8 a[4], b[4];
        #pragma unroll
        for (int mi = 0; mi < 4; ++mi)
            a[mi] = *(const short8*)(&hs[mi * 16 + lr][kk * 32 + lk]);
        #pragma unroll
        for (int ni = 0; ni < 4; ++ni)
            b[ni] = *(const short8*)(&innT[w][ni * 16 + lr][kk * 32 + lk]);
        #pragma unroll
        for (int mi = 0; mi < 4; ++mi)
            #pragma unroll
            for (int ni = 0; ni < 4; ++ni)
                acc[mi][ni] = __builtin_amdgcn_mfma_f32_16x16x32_bf16(a[mi], b[ni], acc[mi][ni], 0, 0, 0);
    }

    const int rin = (lane >> 4) * 4;
    #pragma unroll
    for (int mi = 0; mi < 4; ++mi) {
        #pragma unroll
        for (int ni = 0; ni < 4; ++ni) {
            int y = ni * 16 + lr;
            #pragma unroll
            for (int j = 0; j < 4; ++j) {
                int b = b0 + mi * 16 + rin + j;
                T[((size_t)b * 64 + y) * KMID + w * 64 + i] = f2bf(acc[mi][ni][j]);
            }
        }
    }
}

// ---------------- stage 3: out[(b,y)][o] = t2 @ outer^T  (LDS-free MFMA) ---
__global__ __launch_bounds__(256) void stage3(
    const unsigned short* __restrict__ T,   // [131072][256] bf16
    const unsigned short* __restrict__ Ob,  // [1024][256] bf16
    float* __restrict__ out)                // [2048][65536] f32
{
    const int tid = threadIdx.x;
    const int lane = tid & 63;
    const int w = tid >> 6;
    const int wm = w >> 1, wn = w & 1;
    const int bx = blockIdx.x;
    const int mb = bx >> 3;   // 1024 M-tiles; 8 consecutive blocks share A panel
    const int nb = bx & 7;
    const int by0 = mb * 128 + wm * 64;
    const int o0 = nb * 128 + wn * 64;
    const int lr = lane & 15;
    const int lk = (lane >> 4) * 8;

    f32x4 acc[4][4] = {};
    #pragma unroll
    for (int kt = 0; kt < 8; ++kt) {
        short8 a[4], b[4];
        #pragma unroll
        for (int mi = 0; mi < 4; ++mi)
            a[mi] = *(const short8*)(T + (size_t)(by0 + mi * 16 + lr) * KMID + kt * 32 + lk);
        #pragma unroll
        for (int ni = 0; ni < 4; ++ni)
            b[ni] = *(const short8*)(Ob + (size_t)(o0 + ni * 16 + lr) * KMID + kt * 32 + lk);
        #pragma unroll
        for (int mi = 0; mi < 4; ++mi)
            #pragma unroll
            for (int ni = 0; ni < 4; ++ni)
                acc[mi][ni] = __builtin_amdgcn_mfma_f32_16x16x32_bf16(a[mi], b[ni], acc[mi][ni], 0, 0, 0);
    }

    const int rin = (lane >> 4) * 4;
    #pragma unroll
    for (int mi = 0; mi < 4; ++mi) {
        int by = by0 + mi * 16 + rin;
        int bb = by >> 6, y = by & 63;
        #pragma unroll
        for (int ni = 0; ni < 4; ++ni) {
            int o = o0 + ni * 16 + lr;
            *(f32x4*)(out + (size_t)bb * NUM_LATENTS + o * 64 + y) = acc[mi][ni];
        }
    }
}

extern "C" void kernel_launch(void* const* d_in, const int* in_sizes, int n_in,
                              void* d_out, int out_size, void* d_ws, size_t ws_size,
                              hipStream_t stream) {
    const float* x     = (const float*)d_in[0];
    const float* pre_w = (const float*)d_in[1];
    const float* pre_b = (const float*)d_in[2];
    const float* inner = (const float*)d_in[3];
    const float* outer = (const float*)d_in[4];
    float* out = (float*)d_out;

    char* ws = (char*)d_ws;
    unsigned short* x_bf = (unsigned short*)ws;  ws += (size_t)TOKENS * D_IN * 2;
    unsigned short* w_bf = (unsigned short*)ws;  ws += (size_t)D_IN * D_IN * 2;
    unsigned short* o_bf = (unsigned short*)ws;  ws += (size_t)OUT_GROUPS * KMID * 2;
    unsigned short* h_bf = (unsigned short*)ws;  ws += (size_t)TOKENS * D_IN * 2;
    unsigned short* t_bf = (unsigned short*)ws;  ws += (size_t)TOKENS * 64 * KMID * 2;

    // converts
    cvt_bf16<<<(TOKENS * D_IN / 4 + 255) / 256, 256, 0, stream>>>(x, x_bf, TOKENS * D_IN / 4);
    cvt_bf16<<<(D_IN * D_IN / 4 + 255) / 256, 256, 0, stream>>>(pre_w, w_bf, D_IN * D_IN / 4);
    cvt_bf16<<<(OUT_GROUPS * KMID / 4 + 255) / 256, 256, 0, stream>>>(outer, o_bf, OUT_GROUPS * KMID / 4);

    // stage 1: 16 m-tiles x 32 n-tiles
    gemm_pre<<<512, 256, 0, stream>>>(x_bf, w_bf, pre_b, h_bf);
    // stage 2: 64 i x 32 b-tiles
    stage2<<<2048, 256, 0, stream>>>(h_bf, inner, t_bf);
    // stage 3: 1024 M-tiles x 8 N-tiles
    stage3<<<8192, 256, 0, stream>>>(t_bf, o_bf, out);
}

// Round 2
// 401.492 us; speedup vs baseline: 1.6004x; 1.6004x over previous
//
#include <hip/hip_runtime.h>
#include <hip/hip_bf16.h>
#include <stdint.h>

#define D_IN 4096
#define TOKENS 2048
#define NUM_LATENTS 65536
#define GROUP_DIM 64
#define GROUP_MUL 4
#define IN_GROUPS 64
#define OUT_GROUPS 1024
#define KMID 256   // GROUP_MUL * IN_GROUPS, k' = i*4 + m

typedef __attribute__((ext_vector_type(8))) short short8;
typedef __attribute__((ext_vector_type(4))) float f32x4;

struct alignas(8)  US4 { unsigned short v[4]; };
struct alignas(16) US8 { unsigned short v[8]; };

__device__ inline unsigned short f2bf(float f) {
    union { float f; unsigned u; } w{f};
    unsigned r = w.u + 0x7fffu + ((w.u >> 16) & 1u);  // RNE
    return (unsigned short)(r >> 16);
}

__device__ inline void gload_lds16(const void* g, void* l) {
    __builtin_amdgcn_global_load_lds(
        (const __attribute__((address_space(1))) void*)g,
        (__attribute__((address_space(3))) void*)l, 16, 0, 0);
}

// ---------------- convert f32 -> bf16 (vectorized) ----------------
__global__ void cvt_bf16(const float* __restrict__ s, unsigned short* __restrict__ d, int n4) {
    int i = blockIdx.x * blockDim.x + threadIdx.x;
    if (i < n4) {
        f32x4 v = *(const f32x4*)(s + (size_t)i * 4);
        US4 o;
        #pragma unroll
        for (int j = 0; j < 4; ++j) o.v[j] = f2bf(v[j]);
        *(US4*)(d + (size_t)i * 4) = o;
    }
}

// outer[o][m][i] f32  ->  outerB[o][i*4+m] bf16  (k'-major for stage3 A-frags)
__global__ void cvt_outer_perm(const float* __restrict__ s, unsigned short* __restrict__ d) {
    int t = blockIdx.x * blockDim.x + threadIdx.x;   // 262144
    int o = t >> 8, r = t & 255, m = r >> 6, i = r & 63;
    d[(o << 8) + i * 4 + m] = f2bf(s[t]);
}

// ---------------- stage 1: h = x @ W^T + b   (bf16 MFMA, 128x128x64) -------
__global__ __launch_bounds__(256) void gemm_pre(
    const unsigned short* __restrict__ A,   // x_bf  [2048][4096]
    const unsigned short* __restrict__ B,   // w_bf  [4096][4096] row n, col k
    const float* __restrict__ bias,         // [4096]
    unsigned short* __restrict__ H)         // h_bf  [2048][4096]
{
    __shared__ unsigned short As[128 * 64];
    __shared__ unsigned short Bs[128 * 64];
    const int tid = threadIdx.x;
    const int lane = tid & 63;
    const int w = tid >> 6;
    const int wm = w >> 1, wn = w & 1;
    const int bx = blockIdx.x;
    const int m0 = (bx & 15) * 128;   // 16 m-tiles fast: share B panel in L2
    const int n0 = (bx >> 4) * 128;   // 32 n-tiles

    const int lr = lane & 15;
    const int lk = (lane >> 4) * 8;

    f32x4 acc[4][4] = {};

    for (int k0 = 0; k0 < D_IN; k0 += 64) {
        #pragma unroll
        for (int c = 0; c < 4; ++c) {
            int f = c * 2048 + tid * 8;     // element offset in 128x64 tile
            int r = f >> 6, col = f & 63;
            gload_lds16(A + (size_t)(m0 + r) * D_IN + k0 + col, As + f);
            gload_lds16(B + (size_t)(n0 + r) * D_IN + k0 + col, Bs + f);
        }
        asm volatile("s_waitcnt vmcnt(0)" ::: "memory");
        __syncthreads();
        #pragma unroll
        for (int kk = 0; kk < 2; ++kk) {
            short8 a[4], b[4];
            #pragma unroll
            for (int mi = 0; mi < 4; ++mi)
                a[mi] = *(const short8*)(As + (wm * 64 + mi * 16 + lr) * 64 + kk * 32 + lk);
            #pragma unroll
            for (int ni = 0; ni < 4; ++ni)
                b[ni] = *(const short8*)(Bs + (wn * 64 + ni * 16 + lr) * 64 + kk * 32 + lk);
            #pragma unroll
            for (int mi = 0; mi < 4; ++mi)
                #pragma unroll
                for (int ni = 0; ni < 4; ++ni)
                    acc[mi][ni] = __builtin_amdgcn_mfma_f32_16x16x32_bf16(a[mi], b[ni], acc[mi][ni], 0, 0, 0);
        }
        __syncthreads();
    }

    const int rin = (lane >> 4) * 4;
    #pragma unroll
    for (int ni = 0; ni < 4; ++ni) {
        int col = n0 + wn * 64 + ni * 16 + lr;
        float bv = bias[col];
        #pragma unroll
        for (int mi = 0; mi < 4; ++mi) {
            #pragma unroll
            for (int j = 0; j < 4; ++j) {
                int row = m0 + wm * 64 + mi * 16 + rin + j;
                H[(size_t)row * D_IN + col] = f2bf(acc[mi][ni][j] + bv);
            }
        }
    }
}

// ---------------- stage 2: t[b][i*4+m][y] = sum_x h[b,i,x] inner[m,i,x,y]
// one block per (i, 64-row b-tile); wave w handles m=w. y-contiguous stores.
__global__ __launch_bounds__(256) void stage2(
    const unsigned short* __restrict__ H,   // [2048][4096] bf16
    const float* __restrict__ inner,        // [4][64][64][64] f32
    unsigned short* __restrict__ T)         // [2048][256][64] bf16
{
    __shared__ unsigned short hs[64][80];        // padded
    __shared__ unsigned short innT[4][64][80];   // [m][y][x]
    const int tid = threadIdx.x;
    const int lane = tid & 63;
    const int w = tid >> 6;      // = m
    const int bx = blockIdx.x;
    const int i = bx & 63;
    const int b0 = (bx >> 6) * 64;

    // h tile 64x64 -> padded LDS
    {
        int r = tid >> 2, c = (tid & 3) * 16;
        const unsigned short* src = H + (size_t)(b0 + r) * D_IN + i * 64 + c;
        short8 v0 = *(const short8*)(src);
        short8 v1 = *(const short8*)(src + 8);
        *(short8*)(&hs[r][c]) = v0;
        *(short8*)(&hs[r][c + 8]) = v1;
    }
    // inner[m][i] transposed -> innT[m][y][x], bf16
    {
        const float* src = inner + ((size_t)w * 64 + i) * 4096;  // [x][y]
        #pragma unroll
        for (int p = 0; p < 16; ++p) {
            int idx = p * 256 + lane * 4;
            int x = idx >> 6, y = idx & 63;
            f32x4 v = *(const f32x4*)(src + idx);
            #pragma unroll
            for (int j = 0; j < 4; ++j) innT[w][y + j][x] = f2bf(v[j]);
        }
    }
    __syncthreads();

    const int lr = lane & 15;
    const int lk = (lane >> 4) * 8;
    f32x4 acc[4][4] = {};
    #pragma unroll
    for (int kk = 0; kk < 2; ++kk) {
        short8 a[4], b[4];
        #pragma unroll
        for (int mi = 0; mi < 4; ++mi)
            a[mi] = *(const short8*)(&hs[mi * 16 + lr][kk * 32 + lk]);
        #pragma unroll
        for (int ni = 0; ni < 4; ++ni)
            b[ni] = *(const short8*)(&innT[w][ni * 16 + lr][kk * 32 + lk]);
        #pragma unroll
        for (int mi = 0; mi < 4; ++mi)
            #pragma unroll
            for (int ni = 0; ni < 4; ++ni)
                acc[mi][ni] = __builtin_amdgcn_mfma_f32_16x16x32_bf16(a[mi], b[ni], acc[mi][ni], 0, 0, 0);
    }

    const int rin = (lane >> 4) * 4;
    const int kp = i * 4 + w;   // k' = i*4 + m
    #pragma unroll
    for (int mi = 0; mi < 4; ++mi) {
        #pragma unroll
        for (int ni = 0; ni < 4; ++ni) {
            int y = ni * 16 + lr;
            #pragma unroll
            for (int j = 0; j < 4; ++j) {
                int bb = b0 + mi * 16 + rin + j;
                T[((size_t)bb * KMID + kp) * 64 + y] = f2bf(acc[mi][ni][j]);
            }
        }
    }
}

// ---------------- stage 3: out[b][o][y] = sum_k' outerB[o][k'] * t[b][k'][y]
// per-token GEMM M=o(512 per block), N=y(64), K=256. t_b staged in LDS
// transposed [y][k] with XOR swizzle; A-frags direct from L2-resident outerB.
__global__ __launch_bounds__(256) void stage3(
    const unsigned short* __restrict__ T,   // [2048][256][64] bf16
    const unsigned short* __restrict__ Ob,  // [1024][256] bf16 (k'-major)
    float* __restrict__ out)                // [2048][65536] f32
{
    __shared__ char ts[32768];  // [64 y][512 B], byte ^= (y&7)<<4
    const int tid = threadIdx.x;
    const int lane = tid & 63;
    const int w = tid >> 6;
    int bx = blockIdx.x;
    bx = (bx & 7) * 512 + (bx >> 3);   // XCD swizzle (4096 % 8 == 0)
    const int b = bx >> 1;
    const int half = bx & 1;
    const int lr = lane & 15;
    const int hi = lane >> 4;

    // stage t_b (16384 elems, [k][y] y-contig) -> LDS transposed [y][k]
    {
        const unsigned short* src = T + (size_t)b * (KMID * 64);
        #pragma unroll
        for (int c = 0; c < 8; ++c) {
            int e = c * 2048 + tid * 8;
            int k = e >> 6, y = e & 63;     // y multiple of 8
            US8 v = *(const US8*)(src + e);
            #pragma unroll
            for (int j = 0; j < 8; ++j) {
                int addr = (((y + j) << 9) + k * 2) ^ (j << 4);
                *(unsigned short*)(ts + addr) = v.v[j];
            }
        }
    }
    __syncthreads();

    const int o_base = half * 512 + w * 128;
    f32x4 acc[8][4] = {};
    for (int kt = 0; kt < 8; ++kt) {
        short8 a[8], bfrag[4];
        #pragma unroll
        for (int mi = 0; mi < 8; ++mi)
            a[mi] = *(const short8*)(Ob + ((size_t)(o_base + mi * 16 + lr) << 8) + kt * 32 + hi * 8);
        #pragma unroll
        for (int ni = 0; ni < 4; ++ni) {
            int y = ni * 16 + lr;
            int addr = ((y << 9) + kt * 64 + hi * 16) ^ ((y & 7) << 4);
            bfrag[ni] = *(const short8*)(ts + addr);
        }
        #pragma unroll
        for (int mi = 0; mi < 8; ++mi)
            #pragma unroll
            for (int ni = 0; ni < 4; ++ni)
                acc[mi][ni] = __builtin_amdgcn_mfma_f32_16x16x32_bf16(a[mi], bfrag[ni], acc[mi][ni], 0, 0, 0);
    }

    float* ob = out + (size_t)b * NUM_LATENTS;
    const int rin = hi * 4;
    #pragma unroll
    for (int mi = 0; mi < 8; ++mi) {
        #pragma unroll
        for (int ni = 0; ni < 4; ++ni) {
            int y = ni * 16 + lr;
            #pragma unroll
            for (int j = 0; j < 4; ++j) {
                int o = o_base + mi * 16 + rin + j;
                ob[(o << 6) + y] = acc[mi][ni][j];   // 16-lane 64B runs, coalesced
            }
        }
    }
}

extern "C" void kernel_launch(void* const* d_in, const int* in_sizes, int n_in,
                              void* d_out, int out_size, void* d_ws, size_t ws_size,
                              hipStream_t stream) {
    const float* x     = (const float*)d_in[0];
    const float* pre_w = (const float*)d_in[1];
    const float* pre_b = (const float*)d_in[2];
    const float* inner = (const float*)d_in[3];
    const float* outer = (const float*)d_in[4];
    float* out = (float*)d_out;

    char* ws = (char*)d_ws;
    unsigned short* x_bf = (unsigned short*)ws;  ws += (size_t)TOKENS * D_IN * 2;
    unsigned short* w_bf = (unsigned short*)ws;  ws += (size_t)D_IN * D_IN * 2;
    unsigned short* o_bf = (unsigned short*)ws;  ws += (size_t)OUT_GROUPS * KMID * 2;
    unsigned short* h_bf = (unsigned short*)ws;  ws += (size_t)TOKENS * D_IN * 2;
    unsigned short* t_bf = (unsigned short*)ws;  ws += (size_t)TOKENS * KMID * 64 * 2;

    cvt_bf16<<<(TOKENS * D_IN / 4 + 255) / 256, 256, 0, stream>>>(x, x_bf, TOKENS * D_IN / 4);
    cvt_bf16<<<(D_IN * D_IN / 4 + 255) / 256, 256, 0, stream>>>(pre_w, w_bf, D_IN * D_IN / 4);
    cvt_outer_perm<<<OUT_GROUPS * KMID / 256, 256, 0, stream>>>(outer, o_bf);

    gemm_pre<<<512, 256, 0, stream>>>(x_bf, w_bf, pre_b, h_bf);
    stage2<<<2048, 256, 0, stream>>>(h_bf, inner, t_bf);
    stage3<<<4096, 256, 0, stream>>>(t_bf, o_bf, out);
}